// Round 2
// baseline (1819.141 us; speedup 1.0000x reference)
//
#include <hip/hip_runtime.h>
#include <math.h>

#define PLANE 9216        // 96*96
#define VOL   884736      // 96*96*96
#define NC    4
#define K     7
#define HSR   3
#define SEG   16
#define NSEG  6           // 96/SEG
#define YT    12          // y-tile interior rows for fused y+x kernels
#define YTH   (YT + 6)    // with halo
#define NSLOT 9           // YT*96/128

// ---------------- tables: 1D taps + boundary sums ----------------
__global__ void tables_kernel(const float* __restrict__ sigma2,
                              const float* __restrict__ sigma3,
                              float* __restrict__ taps2, float* __restrict__ taps3,
                              float* __restrict__ B2, float* __restrict__ B3)
{
    int t = threadIdx.x;
    if (t < 2 * NC) {
        int c = t % NC;
        const float* sig = (t < NC) ? sigma2 : sigma3;
        float* taps = (t < NC) ? taps2 : taps3;
        float sv = sig[c];
        float s2 = sv * sv;
        float w[K];
        float sum = 0.f;
        for (int j = 0; j < K; j++) {
            float d = (float)(j - HSR);
            w[j] = expf(-d * d / (2.f * s2));
            sum += w[j];
        }
        float inv = 1.f / sum;   // sum3d = sum^3; per-axis norm by sum reproduces it
        for (int j = 0; j < K; j++) taps[c * K + j] = w[j] * inv;
    }
    __syncthreads();
    for (int i = t; i < NC * 96; i += blockDim.x) {
        int c = i / 96, p = i % 96;
        float s2v = 0.f, s3v = 0.f;
        for (int j = 0; j < K; j++) {
            int q = p + j - HSR;
            if (q >= 0 && q < 96) { s2v += taps2[c * K + j]; s3v += taps3[c * K + j]; }
        }
        B2[i] = s2v;
        B3[i] = s3v;
    }
}

// ---------------- initial softmax over C ----------------
__global__ __launch_bounds__(256) void softmax0_kernel(const float* __restrict__ o,
                                                       const float* __restrict__ eta,
                                                       float* __restrict__ u)
{
    int i = blockIdx.x * 256 + threadIdx.x;
    float inv_eta = 1.f / eta[0];
    float a0 = o[i] * inv_eta;
    float a1 = o[i + VOL] * inv_eta;
    float a2 = o[i + 2 * VOL] * inv_eta;
    float a3 = o[i + 3 * VOL] * inv_eta;
    float m = fmaxf(fmaxf(a0, a1), fmaxf(a2, a3));
    float e0 = __expf(a0 - m), e1 = __expf(a1 - m), e2 = __expf(a2 - m), e3 = __expf(a3 - m);
    float inv = 1.f / (e0 + e1 + e2 + e3);
    u[i] = e0 * inv;
    u[i + VOL] = e1 * inv;
    u[i + 2 * VOL] = e2 * inv;
    u[i + 3 * VOL] = e3 * inv;
}

// ---------------- K1: z-conv of {u*I, u (ker_lif), u (ker)} ----------------
__global__ __launch_bounds__(256) void pass1_z(const float* __restrict__ u,
                                               const float* __restrict__ I,
                                               const float* __restrict__ taps2,
                                               const float* __restrict__ taps3,
                                               float* __restrict__ a0, float* __restrict__ a1,
                                               float* __restrict__ a2)
{
    int p  = blockIdx.x * 256 + threadIdx.x;
    int s  = blockIdx.y;
    int c  = blockIdx.z;
    int z0 = s * SEG;
    const float* ub = u + c * VOL + p;
    const float* Ib = I + p;
    float t3[K], t2[K];
#pragma unroll
    for (int j = 0; j < K; j++) { t3[j] = taps3[c * K + j]; t2[j] = taps2[c * K + j]; }
    float wu[K], wui[K];
#pragma unroll
    for (int j = 0; j < K - 1; j++) {
        int z = z0 + j - HSR;
        float uv = 0.f, iv = 0.f;
        if (z >= 0 && z < 96) { uv = ub[z * PLANE]; iv = Ib[z * PLANE]; }
        wu[j] = uv; wui[j] = uv * iv;
    }
    float* o0 = a0 + c * VOL + p;
    float* o1 = a1 + c * VOL + p;
    float* o2 = a2 + c * VOL + p;
    for (int k = 0; k < SEG; k++) {
        int z = z0 + k;
        int zl = z + HSR;
        float uv = 0.f, iv = 0.f;
        if (zl < 96) { uv = ub[zl * PLANE]; iv = Ib[zl * PLANE]; }
        wu[K - 1] = uv; wui[K - 1] = uv * iv;
        float s0 = 0.f, s1 = 0.f, s2 = 0.f;
#pragma unroll
        for (int j = 0; j < K; j++) { s0 += t3[j] * wui[j]; s1 += t3[j] * wu[j]; s2 += t2[j] * wu[j]; }
        o0[z * PLANE] = s0;
        o1[z * PLANE] = s1;
        o2[z * PLANE] = s2;
#pragma unroll
        for (int j = 0; j < K - 1; j++) { wu[j] = wu[j + 1]; wui[j] = wui[j + 1]; }
    }
}

// ---------------- fused y-conv + x-conv over one (z, y-tile) slab ----------------
// g points at the (c, z) plane. Produces out[NSLOT] = conv_y(conv_x) at
// voxel m = tid + slot*128 (row = m/96, x = m%96) relative to y0.
__device__ __forceinline__ void conv_yx(const float* __restrict__ g,
                                        int y0, int tid,
                                        const float* __restrict__ tapsrow,
                                        float* __restrict__ lin,
                                        float* __restrict__ mid,
                                        float out[NSLOT])
{
    float t[K];
#pragma unroll
    for (int j = 0; j < K; j++) t[j] = tapsrow[j];
    // load YTH rows (with y halo, zero-padded) of full-x width
    for (int i = tid; i < YTH * 96; i += 128) {
        int r = i / 96, x = i - r * 96;
        int gy = y0 - HSR + r;
        lin[i] = (gy >= 0 && gy < 96) ? g[gy * 96 + x] : 0.f;
    }
    __syncthreads();
    // y-conv
#pragma unroll
    for (int slot = 0; slot < NSLOT; slot++) {
        int m = tid + slot * 128;
        int r = m / 96, x = m - r * 96;
        float s = 0.f;
#pragma unroll
        for (int j = 0; j < K; j++) s += t[j] * lin[(r + j) * 96 + x];
        mid[m] = s;
    }
    __syncthreads();
    // x-conv
#pragma unroll
    for (int slot = 0; slot < NSLOT; slot++) {
        int m = tid + slot * 128;
        int r = m / 96, x = m - r * 96;
        float s = 0.f;
#pragma unroll
        for (int j = 0; j < K; j++) {
            int xx = x + j - HSR;
            if (xx >= 0 && xx < 96) s += t[j] * mid[r * 96 + xx];
        }
        out[slot] = s;
    }
    __syncthreads();  // protect mid before next field reuses buffers
}

// ---------------- K2: fused y+x conv of 3 fields -> Cn, q ----------------
__global__ __launch_bounds__(128) void pass2_yx(const float* __restrict__ a0,
                                                const float* __restrict__ a1,
                                                const float* __restrict__ a2,
                                                const float* __restrict__ taps2,
                                                const float* __restrict__ taps3,
                                                const float* __restrict__ B2,
                                                float* __restrict__ Cn, float* __restrict__ q)
{
    __shared__ float lin[YTH * 96];
    __shared__ float mid[YT * 96];
    int yt = blockIdx.x, z = blockIdx.y, c = blockIdx.z;
    int y0 = yt * YT, tid = threadIdx.x;
    size_t base = (size_t)c * VOL + (size_t)z * PLANE;
    float s0[NSLOT], s1[NSLOT], s2v[NSLOT];
    conv_yx(a0 + base, y0, tid, taps3 + c * K, lin, mid, s0);
    conv_yx(a1 + base, y0, tid, taps3 + c * K, lin, mid, s1);
    conv_yx(a2 + base, y0, tid, taps2 + c * K, lin, mid, s2v);
    float Bz = B2[c * 96 + z];
#pragma unroll
    for (int slot = 0; slot < NSLOT; slot++) {
        int m = tid + slot * 128;
        int r = m / 96, x = m - r * 96;
        int y = y0 + r;
        float Cnv = (s0[slot] + 1e-6f) / (s1[slot] + 1e-6f);
        float qv = Bz * B2[c * 96 + y] * B2[c * 96 + x] - 2.f * s2v[slot];
        Cn[base + y * 96 + x] = Cnv;
        q[base + y * 96 + x]  = qv;
    }
}

// ---------------- K3: z-conv of {Cn, Cn^2} ----------------
__global__ __launch_bounds__(256) void pass4_z(const float* __restrict__ Cn,
                                               const float* __restrict__ taps3,
                                               float* __restrict__ b0, float* __restrict__ b1)
{
    int p  = blockIdx.x * 256 + threadIdx.x;
    int s  = blockIdx.y;
    int c  = blockIdx.z;
    int z0 = s * SEG;
    const float* ib = Cn + c * VOL + p;
    float t3[K];
#pragma unroll
    for (int j = 0; j < K; j++) t3[j] = taps3[c * K + j];
    float w[K];
#pragma unroll
    for (int j = 0; j < K - 1; j++) {
        int z = z0 + j - HSR;
        float v = 0.f;
        if (z >= 0 && z < 96) v = ib[z * PLANE];
        w[j] = v;
    }
    float* o0 = b0 + c * VOL + p;
    float* o1 = b1 + c * VOL + p;
    for (int k = 0; k < SEG; k++) {
        int z = z0 + k, zl = z + HSR;
        float v = 0.f;
        if (zl < 96) v = ib[zl * PLANE];
        w[K - 1] = v;
        float s0 = 0.f, s1 = 0.f;
#pragma unroll
        for (int j = 0; j < K; j++) { s0 += t3[j] * w[j]; s1 += t3[j] * w[j] * w[j]; }
        o0[z * PLANE] = s0;
        o1[z * PLANE] = s1;
#pragma unroll
        for (int j = 0; j < K - 1; j++) w[j] = w[j + 1];
    }
}

// ---------------- K4: fused y+x conv (4c x 2 fields) + Lif + softmax ----------------
__global__ __launch_bounds__(128) void pass4_yx_final(const float* __restrict__ c0,
                                                      const float* __restrict__ c1,
                                                      const float* __restrict__ q,
                                                      const float* __restrict__ o,
                                                      const float* __restrict__ I,
                                                      const float* __restrict__ taps3,
                                                      const float* __restrict__ B3,
                                                      const float* __restrict__ eta,
                                                      const float* __restrict__ lam,
                                                      const float* __restrict__ mu,
                                                      float* __restrict__ u)
{
    __shared__ float lin[YTH * 96];
    __shared__ float mid[YT * 96];
    int yt = blockIdx.x, z = blockIdx.y;
    int y0 = yt * YT, tid = threadIdx.x;
    float inv_eta = 1.f / eta[0];
    float lamv = lam[0], muv = mu[0];
    float arg[NC][NSLOT];
#pragma unroll
    for (int c = 0; c < NC; c++) {
        size_t base = (size_t)c * VOL + (size_t)z * PLANE;
        float d0[NSLOT], d1[NSLOT];
        conv_yx(c0 + base, y0, tid, taps3 + c * K, lin, mid, d0);
        conv_yx(c1 + base, y0, tid, taps3 + c * K, lin, mid, d1);
        float Bz = B3[c * 96 + z];
#pragma unroll
        for (int slot = 0; slot < NSLOT; slot++) {
            int m = tid + slot * 128;
            int r = m / 96, x = m - r * 96;
            int y = y0 + r;
            int v = z * PLANE + y * 96 + x;
            float Iv = I[v];
            float cones = Bz * B3[c * 96 + y] * B3[c * 96 + x];
            float Lif = d1[slot] - 2.f * Iv * d0[slot] + Iv * Iv * cones;
            arg[c][slot] = (o[c * VOL + v] - muv * Lif - lamv * q[c * VOL + v]) * inv_eta;
        }
    }
#pragma unroll
    for (int slot = 0; slot < NSLOT; slot++) {
        int m = tid + slot * 128;
        int r = m / 96, x = m - r * 96;
        int v = z * PLANE + (y0 + r) * 96 + x;
        float mx = fmaxf(fmaxf(arg[0][slot], arg[1][slot]), fmaxf(arg[2][slot], arg[3][slot]));
        float e0 = __expf(arg[0][slot] - mx), e1 = __expf(arg[1][slot] - mx);
        float e2 = __expf(arg[2][slot] - mx), e3 = __expf(arg[3][slot] - mx);
        float inv = 1.f / (e0 + e1 + e2 + e3);
        u[v] = e0 * inv;
        u[v + VOL] = e1 * inv;
        u[v + 2 * VOL] = e2 * inv;
        u[v + 3 * VOL] = e3 * inv;
    }
}

extern "C" void kernel_launch(void* const* d_in, const int* in_sizes, int n_in,
                              void* d_out, int out_size, void* d_ws, size_t ws_size,
                              hipStream_t stream)
{
    const float* o      = (const float*)d_in[0];
    const float* I      = (const float*)d_in[1];
    const float* sigma2 = (const float*)d_in[2];
    const float* sigma3 = (const float*)d_in[3];
    const float* eta    = (const float*)d_in[4];
    const float* lam    = (const float*)d_in[5];
    const float* mu     = (const float*)d_in[6];
    float* u = (float*)d_out;

    float* wsf = (float*)d_ws;
    float* taps2 = wsf;              // 28 floats
    float* taps3 = wsf + 32;
    float* B2    = wsf + 64;         // 384 floats
    float* B3    = wsf + 64 + NC * 96;
    float* buf   = wsf + 1024;
    const size_t VCs = (size_t)NC * VOL;
    float* a0 = buf;                 // z-conv outs
    float* a1 = buf + VCs;
    float* a2 = buf + 2 * VCs;
    float* Cn = buf + 3 * VCs;
    float* qb = buf + 4 * VCs;
    float* c0 = buf + 5 * VCs;       // z-conv of Cn, Cn^2
    float* c1 = buf + 6 * VCs;

    const dim3 gridZ(PLANE / 256, NSEG, NC);   // 36 x 6 x 4 = 864 blocks
    const dim3 gridYX(96 / YT, 96, NC);        // 8 x 96 x 4 = 3072 blocks
    const dim3 gridYXF(96 / YT, 96);           // 8 x 96 = 768 blocks
    const int gridV = VOL / 256;               // 3456

    tables_kernel<<<1, 512, 0, stream>>>(sigma2, sigma3, taps2, taps3, B2, B3);
    softmax0_kernel<<<gridV, 256, 0, stream>>>(o, eta, u);
    for (int it = 0; it < 10; it++) {
        pass1_z<<<gridZ, 256, 0, stream>>>(u, I, taps2, taps3, a0, a1, a2);
        pass2_yx<<<gridYX, 128, 0, stream>>>(a0, a1, a2, taps2, taps3, B2, Cn, qb);
        pass4_z<<<gridZ, 256, 0, stream>>>(Cn, taps3, c0, c1);
        pass4_yx_final<<<gridYXF, 128, 0, stream>>>(c0, c1, qb, o, I, taps3, B3,
                                                    eta, lam, mu, u);
    }
}

// Round 3
// 919.655 us; speedup vs baseline: 1.9781x; 1.9781x over previous
//
#include <hip/hip_runtime.h>
#include <math.h>

#define PLANE 9216        // 96*96
#define VOL   884736      // 96*96*96
#define NC    4
#define K     7
#define HSR   3
#define SEG   16
#define NSEG  6           // 96/SEG
#define YT    12          // y-tile interior rows for fused y+x kernels
#define YTH   (YT + 6)    // with halo
#define NSLOT 9           // YT*96/128

// ---------------- tables: 1D taps + boundary sums ----------------
__global__ void tables_kernel(const float* __restrict__ sigma2,
                              const float* __restrict__ sigma3,
                              float* __restrict__ taps2, float* __restrict__ taps3,
                              float* __restrict__ B2, float* __restrict__ B3)
{
    int t = threadIdx.x;
    if (t < 2 * NC) {
        int c = t % NC;
        const float* sig = (t < NC) ? sigma2 : sigma3;
        float* taps = (t < NC) ? taps2 : taps3;
        float sv = sig[c];
        float s2 = sv * sv;
        float w[K];
        float sum = 0.f;
        for (int j = 0; j < K; j++) {
            float d = (float)(j - HSR);
            w[j] = expf(-d * d / (2.f * s2));
            sum += w[j];
        }
        float inv = 1.f / sum;   // sum3d = sum^3; per-axis norm by sum reproduces it
        for (int j = 0; j < K; j++) taps[c * K + j] = w[j] * inv;
    }
    __syncthreads();
    for (int i = t; i < NC * 96; i += blockDim.x) {
        int c = i / 96, p = i % 96;
        float s2v = 0.f, s3v = 0.f;
        for (int j = 0; j < K; j++) {
            int q = p + j - HSR;
            if (q >= 0 && q < 96) { s2v += taps2[c * K + j]; s3v += taps3[c * K + j]; }
        }
        B2[i] = s2v;
        B3[i] = s3v;
    }
}

// ---------------- initial softmax over C ----------------
__global__ __launch_bounds__(256) void softmax0_kernel(const float* __restrict__ o,
                                                       const float* __restrict__ eta,
                                                       float* __restrict__ u)
{
    int i = blockIdx.x * 256 + threadIdx.x;
    float inv_eta = 1.f / eta[0];
    float a0 = o[i] * inv_eta;
    float a1 = o[i + VOL] * inv_eta;
    float a2 = o[i + 2 * VOL] * inv_eta;
    float a3 = o[i + 3 * VOL] * inv_eta;
    float m = fmaxf(fmaxf(a0, a1), fmaxf(a2, a3));
    float e0 = __expf(a0 - m), e1 = __expf(a1 - m), e2 = __expf(a2 - m), e3 = __expf(a3 - m);
    float inv = 1.f / (e0 + e1 + e2 + e3);
    u[i] = e0 * inv;
    u[i + VOL] = e1 * inv;
    u[i + 2 * VOL] = e2 * inv;
    u[i + 3 * VOL] = e3 * inv;
}

// ---------------- K1: z-conv of {u*I, u (ker_lif), u (ker)} ----------------
__global__ __launch_bounds__(256) void pass1_z(const float* __restrict__ u,
                                               const float* __restrict__ I,
                                               const float* __restrict__ taps2,
                                               const float* __restrict__ taps3,
                                               float* __restrict__ a0, float* __restrict__ a1,
                                               float* __restrict__ a2)
{
    int p  = blockIdx.x * 256 + threadIdx.x;
    int s  = blockIdx.y;
    int c  = blockIdx.z;
    int z0 = s * SEG;
    const float* ub = u + c * VOL + p;
    const float* Ib = I + p;
    float t3[K], t2[K];
#pragma unroll
    for (int j = 0; j < K; j++) { t3[j] = taps3[c * K + j]; t2[j] = taps2[c * K + j]; }
    float wu[K], wui[K];
#pragma unroll
    for (int j = 0; j < K - 1; j++) {
        int z = z0 + j - HSR;
        float uv = 0.f, iv = 0.f;
        if (z >= 0 && z < 96) { uv = ub[z * PLANE]; iv = Ib[z * PLANE]; }
        wu[j] = uv; wui[j] = uv * iv;
    }
    float* o0 = a0 + c * VOL + p;
    float* o1 = a1 + c * VOL + p;
    float* o2 = a2 + c * VOL + p;
    for (int k = 0; k < SEG; k++) {
        int z = z0 + k;
        int zl = z + HSR;
        float uv = 0.f, iv = 0.f;
        if (zl < 96) { uv = ub[zl * PLANE]; iv = Ib[zl * PLANE]; }
        wu[K - 1] = uv; wui[K - 1] = uv * iv;
        float s0 = 0.f, s1 = 0.f, s2 = 0.f;
#pragma unroll
        for (int j = 0; j < K; j++) { s0 += t3[j] * wui[j]; s1 += t3[j] * wu[j]; s2 += t2[j] * wu[j]; }
        o0[z * PLANE] = s0;
        o1[z * PLANE] = s1;
        o2[z * PLANE] = s2;
#pragma unroll
        for (int j = 0; j < K - 1; j++) { wu[j] = wu[j + 1]; wui[j] = wui[j + 1]; }
    }
}

// ---------------- fused y-conv + x-conv over one (z, y-tile) slab ----------------
__device__ __forceinline__ void conv_yx(const float* __restrict__ g,
                                        int y0, int tid,
                                        const float* __restrict__ tapsrow,
                                        float* __restrict__ lin,
                                        float* __restrict__ mid,
                                        float out[NSLOT])
{
    float t[K];
#pragma unroll
    for (int j = 0; j < K; j++) t[j] = tapsrow[j];
    for (int i = tid; i < YTH * 96; i += 128) {
        int r = i / 96, x = i - r * 96;
        int gy = y0 - HSR + r;
        lin[i] = (gy >= 0 && gy < 96) ? g[gy * 96 + x] : 0.f;
    }
    __syncthreads();
#pragma unroll
    for (int slot = 0; slot < NSLOT; slot++) {
        int m = tid + slot * 128;
        int r = m / 96, x = m - r * 96;
        float s = 0.f;
#pragma unroll
        for (int j = 0; j < K; j++) s += t[j] * lin[(r + j) * 96 + x];
        mid[m] = s;
    }
    __syncthreads();
#pragma unroll
    for (int slot = 0; slot < NSLOT; slot++) {
        int m = tid + slot * 128;
        int r = m / 96, x = m - r * 96;
        float s = 0.f;
#pragma unroll
        for (int j = 0; j < K; j++) {
            int xx = x + j - HSR;
            if (xx >= 0 && xx < 96) s += t[j] * mid[r * 96 + xx];
        }
        out[slot] = s;
    }
    __syncthreads();
}

// ---------------- K2: fused y+x conv of 3 fields -> Cn, q ----------------
__global__ __launch_bounds__(128) void pass2_yx(const float* __restrict__ a0,
                                                const float* __restrict__ a1,
                                                const float* __restrict__ a2,
                                                const float* __restrict__ taps2,
                                                const float* __restrict__ taps3,
                                                const float* __restrict__ B2,
                                                float* __restrict__ Cn, float* __restrict__ q)
{
    __shared__ float lin[YTH * 96];
    __shared__ float mid[YT * 96];
    int yt = blockIdx.x, z = blockIdx.y, c = blockIdx.z;
    int y0 = yt * YT, tid = threadIdx.x;
    size_t base = (size_t)c * VOL + (size_t)z * PLANE;
    float s0[NSLOT], s1[NSLOT], s2v[NSLOT];
    conv_yx(a0 + base, y0, tid, taps3 + c * K, lin, mid, s0);
    conv_yx(a1 + base, y0, tid, taps3 + c * K, lin, mid, s1);
    conv_yx(a2 + base, y0, tid, taps2 + c * K, lin, mid, s2v);
    float Bz = B2[c * 96 + z];
#pragma unroll
    for (int slot = 0; slot < NSLOT; slot++) {
        int m = tid + slot * 128;
        int r = m / 96, x = m - r * 96;
        int y = y0 + r;
        float Cnv = (s0[slot] + 1e-6f) / (s1[slot] + 1e-6f);
        float qv = Bz * B2[c * 96 + y] * B2[c * 96 + x] - 2.f * s2v[slot];
        Cn[base + y * 96 + x] = Cnv;
        q[base + y * 96 + x]  = qv;
    }
}

// ---------------- K3: z-conv of {Cn, Cn^2} ----------------
__global__ __launch_bounds__(256) void pass4_z(const float* __restrict__ Cn,
                                               const float* __restrict__ taps3,
                                               float* __restrict__ b0, float* __restrict__ b1)
{
    int p  = blockIdx.x * 256 + threadIdx.x;
    int s  = blockIdx.y;
    int c  = blockIdx.z;
    int z0 = s * SEG;
    const float* ib = Cn + c * VOL + p;
    float t3[K];
#pragma unroll
    for (int j = 0; j < K; j++) t3[j] = taps3[c * K + j];
    float w[K];
#pragma unroll
    for (int j = 0; j < K - 1; j++) {
        int z = z0 + j - HSR;
        float v = 0.f;
        if (z >= 0 && z < 96) v = ib[z * PLANE];
        w[j] = v;
    }
    float* o0 = b0 + c * VOL + p;
    float* o1 = b1 + c * VOL + p;
    for (int k = 0; k < SEG; k++) {
        int z = z0 + k, zl = z + HSR;
        float v = 0.f;
        if (zl < 96) v = ib[zl * PLANE];
        w[K - 1] = v;
        float s0 = 0.f, s1 = 0.f;
#pragma unroll
        for (int j = 0; j < K; j++) { s0 += t3[j] * w[j]; s1 += t3[j] * w[j] * w[j]; }
        o0[z * PLANE] = s0;
        o1[z * PLANE] = s1;
#pragma unroll
        for (int j = 0; j < K - 1; j++) w[j] = w[j + 1];
    }
}

// ---------------- K4: fused y+x conv of {c0,c1} (one channel) + Lif + arg ----------------
__global__ __launch_bounds__(128) void pass5_yx(const float* __restrict__ c0,
                                                const float* __restrict__ c1,
                                                const float* __restrict__ q,
                                                const float* __restrict__ o,
                                                const float* __restrict__ I,
                                                const float* __restrict__ taps3,
                                                const float* __restrict__ B3,
                                                const float* __restrict__ eta,
                                                const float* __restrict__ lam,
                                                const float* __restrict__ mu,
                                                float* __restrict__ argb)
{
    __shared__ float lin[YTH * 96];
    __shared__ float mid[YT * 96];
    int yt = blockIdx.x, z = blockIdx.y, c = blockIdx.z;
    int y0 = yt * YT, tid = threadIdx.x;
    size_t base = (size_t)c * VOL + (size_t)z * PLANE;
    float inv_eta = 1.f / eta[0];
    float lamv = lam[0], muv = mu[0];
    float d0[NSLOT], d1[NSLOT];
    conv_yx(c0 + base, y0, tid, taps3 + c * K, lin, mid, d0);
    conv_yx(c1 + base, y0, tid, taps3 + c * K, lin, mid, d1);
    float Bz = B3[c * 96 + z];
#pragma unroll
    for (int slot = 0; slot < NSLOT; slot++) {
        int m = tid + slot * 128;
        int r = m / 96, x = m - r * 96;
        int y = y0 + r;
        int v = z * PLANE + y * 96 + x;
        float Iv = I[v];
        float cones = Bz * B3[c * 96 + y] * B3[c * 96 + x];
        float Lif = d1[slot] - 2.f * Iv * d0[slot] + Iv * Iv * cones;
        argb[base + y * 96 + x] = (o[c * VOL + v] - muv * Lif - lamv * q[c * VOL + v]) * inv_eta;
    }
}

// ---------------- K5: channel softmax of arg -> u ----------------
__global__ __launch_bounds__(256) void pass6_softmax(const float* __restrict__ argb,
                                                     float* __restrict__ u)
{
    int i = blockIdx.x * 256 + threadIdx.x;
    float a0 = argb[i];
    float a1 = argb[i + VOL];
    float a2 = argb[i + 2 * VOL];
    float a3 = argb[i + 3 * VOL];
    float m = fmaxf(fmaxf(a0, a1), fmaxf(a2, a3));
    float e0 = __expf(a0 - m), e1 = __expf(a1 - m), e2 = __expf(a2 - m), e3 = __expf(a3 - m);
    float inv = 1.f / (e0 + e1 + e2 + e3);
    u[i] = e0 * inv;
    u[i + VOL] = e1 * inv;
    u[i + 2 * VOL] = e2 * inv;
    u[i + 3 * VOL] = e3 * inv;
}

extern "C" void kernel_launch(void* const* d_in, const int* in_sizes, int n_in,
                              void* d_out, int out_size, void* d_ws, size_t ws_size,
                              hipStream_t stream)
{
    const float* o      = (const float*)d_in[0];
    const float* I      = (const float*)d_in[1];
    const float* sigma2 = (const float*)d_in[2];
    const float* sigma3 = (const float*)d_in[3];
    const float* eta    = (const float*)d_in[4];
    const float* lam    = (const float*)d_in[5];
    const float* mu     = (const float*)d_in[6];
    float* u = (float*)d_out;

    float* wsf = (float*)d_ws;
    float* taps2 = wsf;              // 28 floats
    float* taps3 = wsf + 32;
    float* B2    = wsf + 64;         // 384 floats
    float* B3    = wsf + 64 + NC * 96;
    float* buf   = wsf + 1024;
    const size_t VCs = (size_t)NC * VOL;
    float* a0 = buf;                 // z-conv outs; reused as arg buffer
    float* a1 = buf + VCs;
    float* a2 = buf + 2 * VCs;
    float* Cn = buf + 3 * VCs;
    float* qb = buf + 4 * VCs;
    float* c0 = buf + 5 * VCs;       // z-conv of Cn, Cn^2
    float* c1 = buf + 6 * VCs;

    const dim3 gridZ(PLANE / 256, NSEG, NC);   // 36 x 6 x 4 = 864 blocks
    const dim3 gridYX(96 / YT, 96, NC);        // 8 x 96 x 4 = 3072 blocks
    const int gridV = VOL / 256;               // 3456

    tables_kernel<<<1, 512, 0, stream>>>(sigma2, sigma3, taps2, taps3, B2, B3);
    softmax0_kernel<<<gridV, 256, 0, stream>>>(o, eta, u);
    for (int it = 0; it < 10; it++) {
        pass1_z<<<gridZ, 256, 0, stream>>>(u, I, taps2, taps3, a0, a1, a2);
        pass2_yx<<<gridYX, 128, 0, stream>>>(a0, a1, a2, taps2, taps3, B2, Cn, qb);
        pass4_z<<<gridZ, 256, 0, stream>>>(Cn, taps3, c0, c1);
        // a0 is free now; reuse as arg buffer
        pass5_yx<<<gridYX, 128, 0, stream>>>(c0, c1, qb, o, I, taps3, B3,
                                             eta, lam, mu, a0);
        pass6_softmax<<<gridV, 256, 0, stream>>>(a0, u);
    }
}